// Round 6
// baseline (526.848 us; speedup 1.0000x reference)
//
#include <hip/hip_runtime.h>
#include <hip/hip_bf16.h>
#include <stdint.h>

typedef short short8 __attribute__((ext_vector_type(8)));
typedef float f32x4 __attribute__((ext_vector_type(4)));

#define NPB  100    // n-rows per block; 1000 blocks * 100 = 100000 exactly

__device__ __forceinline__ uint32_t f32_to_bf16_rne(float f) {
    uint32_t u = __builtin_bit_cast(uint32_t, f);
    uint32_t r = u + 0x7FFFu + ((u >> 16) & 1u);
    return r >> 16;
}
// packed f32x2 -> bf16x2 (RNE), single VALU op
__device__ __forceinline__ uint32_t cvt_pk_bf16(float lo, float hi) {
    uint32_t r;
    asm("v_cvt_pk_bf16_f32 %0, %1, %2" : "=v"(r) : "v"(lo), "v"(hi));
    return r;
}

// ---------------------------------------------------------------------------
// Pre-kernel: Wt[l][o][i] = bf16(w_l[i][o])  (transposed so A-fragments are
// contiguous-in-i 16B loads). 4 * 128 * 128 bf16 = 128 KB in d_ws.
// ---------------------------------------------------------------------------
__global__ void conv_weights(const float* __restrict__ w0, const float* __restrict__ w1,
                             const float* __restrict__ w2, const float* __restrict__ w3,
                             uint16_t* __restrict__ wt) {
    int idx = blockIdx.x * 256 + threadIdx.x;   // 0 .. 65535
    int l = idx >> 14;
    int o = (idx >> 7) & 127;
    int i = idx & 127;
    const float* w = (l == 0) ? w0 : (l == 1) ? w1 : (l == 2) ? w2 : w3;
    wt[idx] = (uint16_t)f32_to_bf16_rne(w[i * 128 + o]);
}

// ---------------------------------------------------------------------------
// Main kernel: NO LDS, NO BARRIERS. 1000 blocks x 512 thr (8 waves).
// Roles swapped vs rounds 1-5: A = weights (in registers, loaded once),
// B = x with c as the MFMA column dim -> direct coalesced global loads.
//   D[o][c] += w_l[i][o] * x[n][i][c]   (one n per MFMA group, K=128)
// Per-c degree l handled by 4 unmasked passes into acc[0..3], then per-lane
// select acc[l(c)] (D col = c = lane&15 is lane-constant).
// Fragments (16x16x32 bf16, m89-verified):
//   A: row=lane&15 (=o_local), k=(lane>>4)*8+j (=i)  -> wt[l][o][i] short8
//   B: col=lane&15 (=c),       k=(lane>>4)*8+j (=i)  -> x[n][i][c] dword loads
//   D: col=lane&15 (=c), row=(lane>>4)*4+reg (=o_local)
// Wave w owns o-tile w; 8 waves share the block's n-range (x via L1/L2).
// 2-deep pipeline: loads for n+1 in flight across compute(n); vmcnt never
// drained by any barrier (there are none).
// ---------------------------------------------------------------------------
__global__ void __launch_bounds__(512)
isl_kernel(const float* __restrict__ x,
           const uint16_t* __restrict__ wt,
           float* __restrict__ out) {
    const int tid  = threadIdx.x;
    const int lane = tid & 63;
    const int wid  = tid >> 6;      // 0..7 = o-tile
    const int r16  = lane & 15;     // A-row (o_local) / B-col & D-col (c)
    const int kg   = lane >> 4;     // 0..3

    // ---- weight fragments, resident in registers for the whole block
    short8 wfr[4][4];               // [l][ks]
    {
        const uint16_t* wb = wt + (size_t)(wid * 16 + r16) * 128 + kg * 8;
        #pragma unroll
        for (int l = 0; l < 4; ++l)
            #pragma unroll
            for (int ks = 0; ks < 4; ++ks)
                wfr[l][ks] = *(const short8*)(wb + l * 16384 + ks * 32);
    }

    const int n0 = blockIdx.x * NPB;
    // per-lane x base: + kg*8 i's (=kg*128 floats) + c
    const float* xl = x + (size_t)n0 * 2048 + kg * 128 + r16;
    // per-lane out base: o = wid*16 + kg*4 (+reg), c = r16
    float* ob = out + (size_t)n0 * 2048 + (size_t)(wid * 16 + kg * 4) * 16 + r16;

    float vA[32], vB[32];

    // ---- issue loads for n0
    #pragma unroll
    for (int ks = 0; ks < 4; ++ks)
        #pragma unroll
        for (int j = 0; j < 8; ++j)
            vA[ks * 8 + j] = xl[(ks * 32 + j) * 16];

    #pragma unroll 1
    for (int nn = 0; nn < NPB; nn += 2) {
        // ---- issue loads for nn+1 (independent; in flight across compute)
        {
            const float* p = xl + (size_t)(nn + 1) * 2048;
            #pragma unroll
            for (int ks = 0; ks < 4; ++ks)
                #pragma unroll
                for (int j = 0; j < 8; ++j)
                    vB[ks * 8 + j] = p[(ks * 32 + j) * 16];
        }
        // ---- compute + store nn (from vA)
        {
            short8 xb[4];
            #pragma unroll
            for (int ks = 0; ks < 4; ++ks) {
                uint32_t q0 = cvt_pk_bf16(vA[ks * 8 + 0], vA[ks * 8 + 1]);
                uint32_t q1 = cvt_pk_bf16(vA[ks * 8 + 2], vA[ks * 8 + 3]);
                uint32_t q2 = cvt_pk_bf16(vA[ks * 8 + 4], vA[ks * 8 + 5]);
                uint32_t q3 = cvt_pk_bf16(vA[ks * 8 + 6], vA[ks * 8 + 7]);
                uint32_t tmp[4] = {q0, q1, q2, q3};
                xb[ks] = *(const short8*)tmp;
            }
            f32x4 acc[4] = {{0,0,0,0},{0,0,0,0},{0,0,0,0},{0,0,0,0}};
            #pragma unroll
            for (int l = 0; l < 4; ++l)
                #pragma unroll
                for (int ks = 0; ks < 4; ++ks)
                    acc[l] = __builtin_amdgcn_mfma_f32_16x16x32_bf16(wfr[l][ks], xb[ks], acc[l], 0, 0, 0);
            float* po = ob + (size_t)nn * 2048;
            #pragma unroll
            for (int r = 0; r < 4; ++r) {
                float v = acc[0][r];
                v = (r16 >= 1) ? acc[1][r] : v;
                v = (r16 >= 4) ? acc[2][r] : v;
                v = (r16 >= 9) ? acc[3][r] : v;
                po[r * 16] = v;
            }
        }
        // ---- issue loads for nn+2 (into vA)
        if (nn + 2 < NPB) {
            const float* p = xl + (size_t)(nn + 2) * 2048;
            #pragma unroll
            for (int ks = 0; ks < 4; ++ks)
                #pragma unroll
                for (int j = 0; j < 8; ++j)
                    vA[ks * 8 + j] = p[(ks * 32 + j) * 16];
        }
        // ---- compute + store nn+1 (from vB)
        {
            short8 xb[4];
            #pragma unroll
            for (int ks = 0; ks < 4; ++ks) {
                uint32_t q0 = cvt_pk_bf16(vB[ks * 8 + 0], vB[ks * 8 + 1]);
                uint32_t q1 = cvt_pk_bf16(vB[ks * 8 + 2], vB[ks * 8 + 3]);
                uint32_t q2 = cvt_pk_bf16(vB[ks * 8 + 4], vB[ks * 8 + 5]);
                uint32_t q3 = cvt_pk_bf16(vB[ks * 8 + 6], vB[ks * 8 + 7]);
                uint32_t tmp[4] = {q0, q1, q2, q3};
                xb[ks] = *(const short8*)tmp;
            }
            f32x4 acc[4] = {{0,0,0,0},{0,0,0,0},{0,0,0,0},{0,0,0,0}};
            #pragma unroll
            for (int l = 0; l < 4; ++l)
                #pragma unroll
                for (int ks = 0; ks < 4; ++ks)
                    acc[l] = __builtin_amdgcn_mfma_f32_16x16x32_bf16(wfr[l][ks], xb[ks], acc[l], 0, 0, 0);
            float* po = ob + (size_t)(nn + 1) * 2048;
            #pragma unroll
            for (int r = 0; r < 4; ++r) {
                float v = acc[0][r];
                v = (r16 >= 1) ? acc[1][r] : v;
                v = (r16 >= 4) ? acc[2][r] : v;
                v = (r16 >= 9) ? acc[3][r] : v;
                po[r * 16] = v;
            }
        }
    }
}

extern "C" void kernel_launch(void* const* d_in, const int* in_sizes, int n_in,
                              void* d_out, int out_size, void* d_ws, size_t ws_size,
                              hipStream_t stream) {
    const float* x  = (const float*)d_in[0];
    const float* w0 = (const float*)d_in[1];
    const float* w1 = (const float*)d_in[2];
    const float* w2 = (const float*)d_in[3];
    const float* w3 = (const float*)d_in[4];
    uint16_t* wt = (uint16_t*)d_ws;          // 128 KB scratch
    float* out = (float*)d_out;

    conv_weights<<<256, 256, 0, stream>>>(w0, w1, w2, w3, wt);
    isl_kernel<<<1000, 512, 0, stream>>>(x, wt, out);
}

// Round 7
// 525.654 us; speedup vs baseline: 1.0023x; 1.0023x over previous
//
#include <hip/hip_runtime.h>
#include <hip/hip_bf16.h>
#include <stdint.h>

typedef short short8 __attribute__((ext_vector_type(8)));
typedef float f32x4 __attribute__((ext_vector_type(4)));

#define NPB  100    // n-rows per block; 1000 blocks * 100 = 100000 exactly

__device__ __forceinline__ uint32_t f32_to_bf16_rne(float f) {
    uint32_t u = __builtin_bit_cast(uint32_t, f);
    uint32_t r = u + 0x7FFFu + ((u >> 16) & 1u);
    return r >> 16;
}
// packed f32x2 -> bf16x2 (RNE), single VALU op
__device__ __forceinline__ uint32_t cvt_pk_bf16(float lo, float hi) {
    uint32_t r;
    asm("v_cvt_pk_bf16_f32 %0, %1, %2" : "=v"(r) : "v"(lo), "v"(hi));
    return r;
}

// ---------------------------------------------------------------------------
// Pre-kernel: Wt[l][o][i] = bf16(w_l[i][o])  (transposed so A-fragments are
// contiguous-in-i 16B loads). 4 * 128 * 128 bf16 = 128 KB in d_ws.
// ---------------------------------------------------------------------------
__global__ void conv_weights(const float* __restrict__ w0, const float* __restrict__ w1,
                             const float* __restrict__ w2, const float* __restrict__ w3,
                             uint16_t* __restrict__ wt) {
    int idx = blockIdx.x * 256 + threadIdx.x;   // 0 .. 65535
    int l = idx >> 14;
    int o = (idx >> 7) & 127;
    int i = idx & 127;
    const float* w = (l == 0) ? w0 : (l == 1) ? w1 : (l == 2) ? w2 : w3;
    wt[idx] = (uint16_t)f32_to_bf16_rne(w[i * 128 + o]);
}

// ---------------------------------------------------------------------------
// Main kernel: NO LDS, NO BARRIERS. 1000 blocks x 512 thr (8 waves).
// A = weights (register-resident), B = x with c as the MFMA column dim ->
// direct coalesced global loads, 2-deep pipeline, vmcnt never force-drained.
//   D[o][c] += w_l[i][o] * x[n][i][c]   (one n per MFMA group, K=128)
// Per-c degree l: 4 unmasked passes into acc[0..3], per-lane select at store.
// Fragments (16x16x32 bf16, m89-verified):
//   A: row=lane&15 (=o_local), k=(lane>>4)*8+j (=i)  -> wt[l][o][i] short8
//   B: col=lane&15 (=c),       k=(lane>>4)*8+j (=i)  -> x[n][i][c] dword loads
//   D: col=lane&15 (=c), row=(lane>>4)*4+reg (=o_local)
//
// __launch_bounds__(512, 1): toolchain A/B (r3: (512,2)->VGPR cap 128;
// r4: (512,4)->cap 64 + scratch spill) => (512,1) -> cap 256. Round 6's plain
// (512) allocated only 72 VGPR, which collapsed the pipeline (steady state
// needs wfr 64 + vA 32 + vB 32 + acc 16 + addr ~= 180) and serialized every
// iteration behind a full load drain -> 3.2 TB/s duty-cycle ceiling.
// ---------------------------------------------------------------------------
__global__ void __launch_bounds__(512, 1)
isl_kernel(const float* __restrict__ x,
           const uint16_t* __restrict__ wt,
           float* __restrict__ out) {
    const int tid  = threadIdx.x;
    const int lane = tid & 63;
    const int wid  = tid >> 6;      // 0..7 = o-tile
    const int r16  = lane & 15;     // A-row (o_local) / B-col & D-col (c)
    const int kg   = lane >> 4;     // 0..3

    // ---- weight fragments, resident in registers for the whole block
    short8 wfr[4][4];               // [l][ks]
    {
        const uint16_t* wb = wt + (size_t)(wid * 16 + r16) * 128 + kg * 8;
        #pragma unroll
        for (int l = 0; l < 4; ++l)
            #pragma unroll
            for (int ks = 0; ks < 4; ++ks)
                wfr[l][ks] = *(const short8*)(wb + l * 16384 + ks * 32);
    }

    const int n0 = blockIdx.x * NPB;
    // per-lane x base: + kg*8 i's (=kg*128 floats) + c
    const float* xl = x + (size_t)n0 * 2048 + kg * 128 + r16;
    // per-lane out base: o = wid*16 + kg*4 (+reg), c = r16
    float* ob = out + (size_t)n0 * 2048 + (size_t)(wid * 16 + kg * 4) * 16 + r16;

    float vA[32], vB[32];

    // ---- issue loads for n0
    #pragma unroll
    for (int ks = 0; ks < 4; ++ks)
        #pragma unroll
        for (int j = 0; j < 8; ++j)
            vA[ks * 8 + j] = xl[(ks * 32 + j) * 16];

    #pragma unroll 1
    for (int nn = 0; nn < NPB; nn += 2) {
        // ---- issue loads for nn+1 (independent; in flight across compute)
        {
            const float* p = xl + (size_t)(nn + 1) * 2048;
            #pragma unroll
            for (int ks = 0; ks < 4; ++ks)
                #pragma unroll
                for (int j = 0; j < 8; ++j)
                    vB[ks * 8 + j] = p[(ks * 32 + j) * 16];
        }
        // ---- compute + store nn (from vA)
        {
            short8 xb[4];
            #pragma unroll
            for (int ks = 0; ks < 4; ++ks) {
                uint32_t q0 = cvt_pk_bf16(vA[ks * 8 + 0], vA[ks * 8 + 1]);
                uint32_t q1 = cvt_pk_bf16(vA[ks * 8 + 2], vA[ks * 8 + 3]);
                uint32_t q2 = cvt_pk_bf16(vA[ks * 8 + 4], vA[ks * 8 + 5]);
                uint32_t q3 = cvt_pk_bf16(vA[ks * 8 + 6], vA[ks * 8 + 7]);
                uint32_t tmp[4] = {q0, q1, q2, q3};
                xb[ks] = *(const short8*)tmp;
            }
            f32x4 acc[4] = {{0,0,0,0},{0,0,0,0},{0,0,0,0},{0,0,0,0}};
            #pragma unroll
            for (int l = 0; l < 4; ++l)
                #pragma unroll
                for (int ks = 0; ks < 4; ++ks)
                    acc[l] = __builtin_amdgcn_mfma_f32_16x16x32_bf16(wfr[l][ks], xb[ks], acc[l], 0, 0, 0);
            float* po = ob + (size_t)nn * 2048;
            #pragma unroll
            for (int r = 0; r < 4; ++r) {
                float v = acc[0][r];
                v = (r16 >= 1) ? acc[1][r] : v;
                v = (r16 >= 4) ? acc[2][r] : v;
                v = (r16 >= 9) ? acc[3][r] : v;
                po[r * 16] = v;
            }
        }
        // ---- issue loads for nn+2 (into vA)
        if (nn + 2 < NPB) {
            const float* p = xl + (size_t)(nn + 2) * 2048;
            #pragma unroll
            for (int ks = 0; ks < 4; ++ks)
                #pragma unroll
                for (int j = 0; j < 8; ++j)
                    vA[ks * 8 + j] = p[(ks * 32 + j) * 16];
        }
        // ---- compute + store nn+1 (from vB)
        {
            short8 xb[4];
            #pragma unroll
            for (int ks = 0; ks < 4; ++ks) {
                uint32_t q0 = cvt_pk_bf16(vB[ks * 8 + 0], vB[ks * 8 + 1]);
                uint32_t q1 = cvt_pk_bf16(vB[ks * 8 + 2], vB[ks * 8 + 3]);
                uint32_t q2 = cvt_pk_bf16(vB[ks * 8 + 4], vB[ks * 8 + 5]);
                uint32_t q3 = cvt_pk_bf16(vB[ks * 8 + 6], vB[ks * 8 + 7]);
                uint32_t tmp[4] = {q0, q1, q2, q3};
                xb[ks] = *(const short8*)tmp;
            }
            f32x4 acc[4] = {{0,0,0,0},{0,0,0,0},{0,0,0,0},{0,0,0,0}};
            #pragma unroll
            for (int l = 0; l < 4; ++l)
                #pragma unroll
                for (int ks = 0; ks < 4; ++ks)
                    acc[l] = __builtin_amdgcn_mfma_f32_16x16x32_bf16(wfr[l][ks], xb[ks], acc[l], 0, 0, 0);
            float* po = ob + (size_t)(nn + 1) * 2048;
            #pragma unroll
            for (int r = 0; r < 4; ++r) {
                float v = acc[0][r];
                v = (r16 >= 1) ? acc[1][r] : v;
                v = (r16 >= 4) ? acc[2][r] : v;
                v = (r16 >= 9) ? acc[3][r] : v;
                po[r * 16] = v;
            }
        }
    }
}

extern "C" void kernel_launch(void* const* d_in, const int* in_sizes, int n_in,
                              void* d_out, int out_size, void* d_ws, size_t ws_size,
                              hipStream_t stream) {
    const float* x  = (const float*)d_in[0];
    const float* w0 = (const float*)d_in[1];
    const float* w1 = (const float*)d_in[2];
    const float* w2 = (const float*)d_in[3];
    const float* w3 = (const float*)d_in[4];
    uint16_t* wt = (uint16_t*)d_ws;          // 128 KB scratch
    float* out = (float*)d_out;

    conv_weights<<<256, 256, 0, stream>>>(w0, w1, w2, w3, wt);
    isl_kernel<<<1000, 512, 0, stream>>>(x, wt, out);
}